// Round 10
// baseline (119.012 us; speedup 1.0000x reference)
//
#include <hip/hip_runtime.h>
#include <hip/hip_bf16.h>
#include <math.h>

#define B_SZ 2048
#define NF 1024
#define NH 2048
#define NCq 128
#define MMq 20
#define NY 2580            // M*NC+M
#define NYPAD 2688         // 21*128
#define QP_ITERS 150

#define XN4  (B_SZ * NF / 4)
#define W1N4 (NH * NF / 4)
#define W2N4 (NY * NH / 4)
#define CVT_TOT (XN4 + W1N4 + W2N4)

typedef unsigned short u16;
typedef __bf16 bf16x8 __attribute__((ext_vector_type(8)));
typedef float f32x4 __attribute__((ext_vector_type(4)));

static __device__ __forceinline__ u16 f32_to_bf16(float f) {
  unsigned u = __float_as_uint(f);
  u += 0x7FFFu + ((u >> 16) & 1u);
  return (u16)(u >> 16);
}

static __device__ __forceinline__ float bcast(float v, int lane) {
  return __uint_as_float(__builtin_amdgcn_readlane(__float_as_uint(v), lane));
}

static __device__ __forceinline__ void gload16(const void* g, void* lds) {
  __builtin_amdgcn_global_load_lds(
      (const __attribute__((address_space(1))) void*)g,
      (__attribute__((address_space(3))) void*)lds, 16, 0, 0);
}

// ---------------- single fused convert: x | W1 | W2(real rows) ----------------
__global__ __launch_bounds__(256) void cvt_all_kernel(const float* __restrict__ x,
                                                      const float* __restrict__ W1,
                                                      const float* __restrict__ W2,
                                                      u16* __restrict__ xb,
                                                      u16* __restrict__ w1b,
                                                      u16* __restrict__ w2b) {
  const int i = blockIdx.x * 256 + threadIdx.x;
  const float* src;
  u16* dst;
  int j;
  if (i < XN4)              { src = x;  dst = xb;  j = i; }
  else if (i < XN4 + W1N4)  { src = W1; dst = w1b; j = i - XN4; }
  else                      { src = W2; dst = w2b; j = i - XN4 - W1N4; }
  float4 v = ((const float4*)src)[j];
  ushort4 o;
  o.x = f32_to_bf16(v.x); o.y = f32_to_bf16(v.y);
  o.z = f32_to_bf16(v.z); o.w = f32_to_bf16(v.w);
  ((ushort4*)dst)[j] = o;
}

// ---------------- GEMM: C = A(MxK) * B(NxK)^T + bias, tile 64x128 ----------------
// 2-phase double-buffered pipeline (T3-minimum template): issue next-tile
// global_load_lds BEFORE computing current tile; single __syncthreads per iter
// (its implicit vmcnt(0) drains loads that now overlap ~200cy of ds_read+MFMA).
// OUTMODE 0: bf16 out with relu (gemm1). OUTMODE 1: f32 out, col<ncols guard (gemm2).
template<int K, int OUTMODE>
__global__ __launch_bounds__(256) void gemm_bt_kernel(
    const u16* __restrict__ A, const u16* __restrict__ Bm,
    const float* __restrict__ bias,
    u16* __restrict__ Cb, float* __restrict__ Cf,
    int ldc, int ncols) {
  __shared__ u16 As[2][64 * 32];    // 2 x 4 KB
  __shared__ u16 Bs[2][128 * 32];   // 2 x 8 KB
  const int tid = threadIdx.x;
  const int w = tid >> 6;
  const int l = tid & 63;
  const int m0 = blockIdx.y * 64;
  const int n0 = blockIdx.x * 128;

  // staging: A = 256 chunks of 16B (1/thread), B = 512 chunks (2/thread)
  // chunk c -> row c>>2, kpart c&3 ; LDS linear at c*16 (wave-uniform base + lane*16)
  const int ca = tid;
  const int cb0 = tid, cb1 = tid + 256;
  const u16* gA0 = A  + (size_t)(m0 + (ca  >> 2)) * K + (ca  & 3) * 8;
  const u16* gB0 = Bm + (size_t)(n0 + (cb0 >> 2)) * K + (cb0 & 3) * 8;
  const u16* gB1 = Bm + (size_t)(n0 + (cb1 >> 2)) * K + (cb1 & 3) * 8;
  char* lA = (char*)As;
  char* lB = (char*)Bs;
  const int lbA  = w * 1024;          // wave-uniform byte offsets within a buffer
  const int lbB0 = w * 1024;
  const int lbB1 = 4096 + w * 1024;

  // wave -> 32x64 output sub-tile: wm in {0,32}, wn in {0,64}
  const int wm = (w >> 1) * 32, wn = (w & 1) * 64;
  const int lrow = l & 15, lk = (l >> 4) * 8;
  int aoff[2], boff[4];
#pragma unroll
  for (int i = 0; i < 2; ++i) aoff[i] = ((wm + i * 16 + lrow) * 32 + lk) * 2;
#pragma unroll
  for (int i = 0; i < 4; ++i) boff[i] = ((wn + i * 16 + lrow) * 32 + lk) * 2;

  f32x4 acc[2][4];
#pragma unroll
  for (int i = 0; i < 2; ++i)
#pragma unroll
    for (int j = 0; j < 4; ++j) acc[i][j] = (f32x4){0.f, 0.f, 0.f, 0.f};

  constexpr int NT = K / 32;

  // prologue: stage tile 0 into buffer 0
  gload16(gA0, lA + lbA);
  gload16(gB0, lB + lbB0);
  gload16(gB1, lB + lbB1);
  __syncthreads();                    // drains vmcnt(0)

  int cur = 0;
  for (int kt = 0; kt < NT; ++kt) {
    // issue next-tile loads first (latency hides under this tile's compute)
    if (kt + 1 < NT) {
      const int nb = cur ^ 1;
      gload16(gA0 + (kt + 1) * 32, lA + nb * 4096 + lbA);
      gload16(gB0 + (kt + 1) * 32, lB + nb * 8192 + lbB0);
      gload16(gB1 + (kt + 1) * 32, lB + nb * 8192 + lbB1);
    }
    bf16x8 af[2], bfr[4];
#pragma unroll
    for (int i = 0; i < 2; ++i) af[i] = *(const bf16x8*)(lA + cur * 4096 + aoff[i]);
#pragma unroll
    for (int i = 0; i < 4; ++i) bfr[i] = *(const bf16x8*)(lB + cur * 8192 + boff[i]);
#pragma unroll
    for (int mi = 0; mi < 2; ++mi)
#pragma unroll
      for (int ni = 0; ni < 4; ++ni)
        acc[mi][ni] = __builtin_amdgcn_mfma_f32_16x16x32_bf16(af[mi], bfr[ni], acc[mi][ni], 0, 0, 0);
    __syncthreads();                  // vmcnt(0)+lgkmcnt(0) drain: next buffer ready
    cur ^= 1;
  }

  // epilogue: C row = m0+wm+mi*16+(l>>4)*4+r ; col = n0+wn+ni*16+(l&15)
#pragma unroll
  for (int mi = 0; mi < 2; ++mi) {
    const int row = m0 + wm + mi * 16 + (l >> 4) * 4;
#pragma unroll
    for (int ni = 0; ni < 4; ++ni) {
      const int col = n0 + wn + ni * 16 + (l & 15);
      if (OUTMODE == 1 && col >= ncols) continue;
      const float bv = bias[col];
#pragma unroll
      for (int r = 0; r < 4; ++r) {
        float v = acc[mi][ni][r] + bv;
        if (OUTMODE == 0) {
          v = fmaxf(v, 0.f);
          Cb[(size_t)(row + r) * ldc + col] = f32_to_bf16(v);
        } else {
          Cf[(size_t)(row + r) * ldc + col] = v;
        }
      }
    }
  }
}

// ---------------- QP solve + log_softmax ----------------
// 4 waves/block, ONE problem per wave (2048 waves -> 2 waves/SIMD). Broadcasts
// via v_readlane (VALU pipe). Waves fully independent: no __syncthreads.
__global__ __launch_bounds__(256) void qp_kernel(const float* __restrict__ y,
                                                 float* __restrict__ out) {
  __shared__ float Gs[4][MMq][132];    // row pad 132: staging/epilogue conflict-free
  __shared__ float GGs[4][MMq][21];    // row pad 21: gcd(21,32)=1, conflict-free
  __shared__ float cs[4][MMq];
  const int tid = threadIdx.x;
  const int wid = tid >> 6, l = tid & 63;
  const int b = blockIdx.x * 4 + wid;
  const float* yb = y + (size_t)b * NY;

  // stage G (20x128) -- own wave only
  for (int idx = l; idx < MMq * NCq / 4; idx += 64) {
    const int r = idx >> 5;
    const int kk = (idx & 31) * 4;
    float4 v = ((const float4*)yb)[idx];
    *(float4*)&Gs[wid][r][kk] = v;
  }

  // GG = G G^T (upper triangle, mirrored) -- own wave
  for (int idx = l; idx < 210; idx += 64) {
    int i = 0, rem = idx;
    while (rem >= MMq - i) { rem -= MMq - i; ++i; }
    const int j = i + rem;
    float s = 0.f;
    for (int kk = 0; kk < NCq; kk += 4) {
      float4 a = *(const float4*)&Gs[wid][i][kk];
      float4 c4 = *(const float4*)&Gs[wid][j][kk];
      s += a.x * c4.x + a.y * c4.y + a.z * c4.z + a.w * c4.w;
    }
    GGs[wid][i][j] = s;
    GGs[wid][j][i] = s;
  }
  // c_i = sum_j G_ij + h_i
  if (l < MMq) {
    float s = 0.f;
    for (int kk = 0; kk < NCq; kk += 4) {
      float4 a = *(const float4*)&Gs[wid][l][kk];
      s += (a.x + a.y) + (a.z + a.w);
    }
    cs[wid][l] = s + yb[MMq * NCq + l];
  }

  const bool act = (l < MMq);
  float gg[MMq];
#pragma unroll
  for (int j = 0; j < MMq; ++j) gg[j] = act ? GGs[wid][l][j] : 0.f;
  const float ci = act ? cs[wid][l] : 0.f;

  // L = max_i sum_j |GG_ij| (inf-norm >= lambda_max; fixed point step-independent)
  float rs = 0.f;
#pragma unroll
  for (int j = 0; j < MMq; ++j) rs += fabsf(gg[j]);
#pragma unroll
  for (int m = 1; m < 64; m <<= 1) rs = fmaxf(rs, __shfl_xor(rs, m, 64));
  const float invL = 1.0f / (rs + 1e-6f);

  // FISTA, momentum beta_k = k/(k+3)
  float lam = 0.f, yv = 0.f, fi = 0.f;
  for (int it = 0; it < QP_ITERS; ++it) {
    float ys[MMq];
#pragma unroll
    for (int j = 0; j < MMq; ++j) ys[j] = bcast(yv, j);   // 20x v_readlane -> SGPR
    float g0 = ci, g1 = 0.f, g2 = 0.f, g3 = 0.f;
#pragma unroll
    for (int j = 0; j < MMq; j += 4) {
      g0 = fmaf(gg[j + 0], ys[j + 0], g0);
      g1 = fmaf(gg[j + 1], ys[j + 1], g1);
      g2 = fmaf(gg[j + 2], ys[j + 2], g2);
      g3 = fmaf(gg[j + 3], ys[j + 3], g3);
    }
    const float grad = (g0 + g1) + (g2 + g3);
    const float ln = fmaxf(fmaf(-grad, invL, yv), 0.f);
    const float beta = fi * __builtin_amdgcn_rcpf(fi + 3.0f);  // off critical path
    yv = fmaf(beta, ln - lam, ln);
    lam = ln;
    fi += 1.0f;
  }

  // broadcast lam to SGPRs; z_j = -(1 + sum_i G_ij lam_i); log_softmax over 128
  float ls[MMq];
#pragma unroll
  for (int j = 0; j < MMq; ++j) ls[j] = bcast(lam, j);

  float z0 = 1.f, z1 = 1.f;
#pragma unroll
  for (int ii = 0; ii < MMq; ++ii) {
    z0 = fmaf(Gs[wid][ii][l], ls[ii], z0);
    z1 = fmaf(Gs[wid][ii][l + 64], ls[ii], z1);
  }
  z0 = -z0; z1 = -z1;

  float mx = fmaxf(z0, z1);
#pragma unroll
  for (int m = 1; m < 64; m <<= 1) mx = fmaxf(mx, __shfl_xor(mx, m, 64));
  float sm = __expf(z0 - mx) + __expf(z1 - mx);
#pragma unroll
  for (int m = 1; m < 64; m <<= 1) sm += __shfl_xor(sm, m, 64);
  const float lse = mx + __logf(sm);
  float* ob = out + (size_t)b * NCq;
  ob[l] = z0 - lse;
  ob[l + 64] = z1 - lse;
}

// ---------------- launch ----------------
extern "C" void kernel_launch(void* const* d_in, const int* in_sizes, int n_in,
                              void* d_out, int out_size, void* d_ws, size_t ws_size,
                              hipStream_t stream) {
  const float* x  = (const float*)d_in[0];
  const float* W1 = (const float*)d_in[1];
  const float* b1 = (const float*)d_in[2];
  const float* W2 = (const float*)d_in[3];
  const float* b2 = (const float*)d_in[4];
  float* out = (float*)d_out;
  char* ws = (char*)d_ws;

  u16*   xb  = (u16*)(ws);                       //  4 MiB: 2048x1024 bf16
  u16*   w1b = (u16*)(ws + 4194304);             //  4 MiB: 2048x1024 bf16
  u16*   w2b = (u16*)(ws + 8388608);             // 10.5 MiB: 2688x2048 bf16 (pad rows
                                                 //   never stored -> left stale, safe)
  u16*   h1b = (u16*)(ws + 19398656);            //  8 MiB: 2048x2048 bf16
  float* yb  = (float*)(ws + 27787264);          // 20.2 MiB: 2048x2580 f32

  cvt_all_kernel<<<CVT_TOT / 256, 256, 0, stream>>>(x, W1, W2, xb, w1b, w2b);

  dim3 g1(NH / 128, B_SZ / 64);
  gemm_bt_kernel<NF, 0><<<g1, 256, 0, stream>>>(xb, w1b, b1, h1b, nullptr, NH, NH);

  dim3 g2(NYPAD / 128, B_SZ / 64);
  gemm_bt_kernel<NH, 1><<<g2, 256, 0, stream>>>(h1b, w2b, b2, nullptr, yb, NY, NY);

  qp_kernel<<<B_SZ / 4, 256, 0, stream>>>(yb, out);
}

// Round 11
// 107.489 us; speedup vs baseline: 1.1072x; 1.1072x over previous
//
#include <hip/hip_runtime.h>
#include <hip/hip_bf16.h>
#include <math.h>

#define B_SZ 2048
#define NF 1024
#define NH 2048
#define NCq 128
#define MMq 20
#define NY 2580            // M*NC+M
#define NYPAD 2688         // 21*128
#define QP_ITERS 150

#define XN4  (B_SZ * NF / 4)
#define W1N4 (NH * NF / 4)
#define W2N4 (NY * NH / 4)
#define CVT_TOT (XN4 + W1N4 + W2N4)

typedef unsigned short u16;
typedef __bf16 bf16x8 __attribute__((ext_vector_type(8)));
typedef float f32x4 __attribute__((ext_vector_type(4)));

static __device__ __forceinline__ u16 f32_to_bf16(float f) {
  unsigned u = __float_as_uint(f);
  u += 0x7FFFu + ((u >> 16) & 1u);
  return (u16)(u >> 16);
}

static __device__ __forceinline__ float bcast(float v, int lane) {
  return __uint_as_float(__builtin_amdgcn_readlane(__float_as_uint(v), lane));
}

static __device__ __forceinline__ void gload16(const void* g, void* lds) {
  __builtin_amdgcn_global_load_lds(
      (const __attribute__((address_space(1))) void*)g,
      (__attribute__((address_space(3))) void*)lds, 16, 0, 0);
}

// ---------------- single fused convert: x | W1 | W2(real rows) ----------------
__global__ __launch_bounds__(256) void cvt_all_kernel(const float* __restrict__ x,
                                                      const float* __restrict__ W1,
                                                      const float* __restrict__ W2,
                                                      u16* __restrict__ xb,
                                                      u16* __restrict__ w1b,
                                                      u16* __restrict__ w2b) {
  const int i = blockIdx.x * 256 + threadIdx.x;
  const float* src;
  u16* dst;
  int j;
  if (i < XN4)              { src = x;  dst = xb;  j = i; }
  else if (i < XN4 + W1N4)  { src = W1; dst = w1b; j = i - XN4; }
  else                      { src = W2; dst = w2b; j = i - XN4 - W1N4; }
  float4 v = ((const float4*)src)[j];
  ushort4 o;
  o.x = f32_to_bf16(v.x); o.y = f32_to_bf16(v.y);
  o.z = f32_to_bf16(v.z); o.w = f32_to_bf16(v.w);
  ((ushort4*)dst)[j] = o;
}

// ---------------- GEMM: C = A(MxK) * B(NxK)^T + bias, tile 64x128 ----------------
// Depth-2 tile pipeline with COUNTED vmcnt (T4, m218): prologue stages tiles 0,1;
// each iter waits vmcnt(6) (current tile's 6 loads retire, next tile's 6 stay in
// flight), raw s_barrier (no implicit vmcnt(0) drain), compute BK=64 (2x32 ksubs),
// barrier, then re-stage tile kt+2 into the freed buffer. Load issue->drain
// distance ~2 iterations (~600cy) covers L2/L3 latency. Last iter peeled, vmcnt(0).
// sched_barrier(0) fences stop ds_read hoist/sink across the waitcnt/re-stage.
// OUTMODE 0: bf16 out with relu (gemm1). OUTMODE 1: f32 out, col<ncols guard (gemm2).
template<int K, int OUTMODE>
__global__ __launch_bounds__(256) void gemm_bt_kernel(
    const u16* __restrict__ A, const u16* __restrict__ Bm,
    const float* __restrict__ bias,
    u16* __restrict__ Cb, float* __restrict__ Cf,
    int ldc, int ncols) {
  __shared__ u16 As[2][2][64 * 32];    // [buf][ksub] 4 KB planes, 16 KB
  __shared__ u16 Bs[2][2][128 * 32];   // [buf][ksub] 8 KB planes, 32 KB
  const int tid = threadIdx.x;
  const int w = tid >> 6;
  const int l = tid & 63;
  const int m0 = blockIdx.y * 64;
  const int n0 = blockIdx.x * 128;

  // per-ksub staging: A = 256 chunks of 16B (1/thread), B = 512 (2/thread)
  // chunk c -> row c>>2, kpart c&3 ; LDS linear at c*16 (wave-uniform base + lane*16)
  const u16* gA0 = A  + (size_t)(m0 + (tid >> 2)) * K + (tid & 3) * 8;
  const u16* gB0 = Bm + (size_t)(n0 + (tid >> 2)) * K + (tid & 3) * 8;
  const u16* gB1 = Bm + (size_t)(n0 + 64 + (tid >> 2)) * K + (tid & 3) * 8;
  char* lA = (char*)As;
  char* lB = (char*)Bs;
  const int lbW = w * 1024;            // wave-uniform byte offset within a plane

  // wave -> 32x64 output sub-tile: wm in {0,32}, wn in {0,64}
  const int wm = (w >> 1) * 32, wn = (w & 1) * 64;
  const int lrow = l & 15, lk = (l >> 4) * 8;
  int aoff[2], boff[4];
#pragma unroll
  for (int i = 0; i < 2; ++i) aoff[i] = ((wm + i * 16 + lrow) * 32 + lk) * 2;
#pragma unroll
  for (int i = 0; i < 4; ++i) boff[i] = ((wn + i * 16 + lrow) * 32 + lk) * 2;

  f32x4 acc[2][4];
#pragma unroll
  for (int i = 0; i < 2; ++i)
#pragma unroll
    for (int j = 0; j < 4; ++j) acc[i][j] = (f32x4){0.f, 0.f, 0.f, 0.f};

  constexpr int NT = K / 64;           // gemm1: 16, gemm2: 32

  auto STAGE = [&](int t, int buf) {   // 6 gload16
#pragma unroll
    for (int ks = 0; ks < 2; ++ks) {
      const int koff = t * 64 + ks * 32;
      gload16(gA0 + koff, lA + buf * 8192  + ks * 4096 + lbW);
      gload16(gB0 + koff, lB + buf * 16384 + ks * 8192 + lbW);
      gload16(gB1 + koff, lB + buf * 16384 + ks * 8192 + 4096 + lbW);
    }
  };
  auto COMPUTE = [&](int buf) {        // 12 ds_read_b128 + 16 MFMA
#pragma unroll
    for (int ks = 0; ks < 2; ++ks) {
      const char* pa = lA + buf * 8192  + ks * 4096;
      const char* pb = lB + buf * 16384 + ks * 8192;
      bf16x8 af[2], bfr[4];
#pragma unroll
      for (int i = 0; i < 2; ++i) af[i] = *(const bf16x8*)(pa + aoff[i]);
#pragma unroll
      for (int i = 0; i < 4; ++i) bfr[i] = *(const bf16x8*)(pb + boff[i]);
#pragma unroll
      for (int mi = 0; mi < 2; ++mi)
#pragma unroll
        for (int ni = 0; ni < 4; ++ni)
          acc[mi][ni] = __builtin_amdgcn_mfma_f32_16x16x32_bf16(af[mi], bfr[ni], acc[mi][ni], 0, 0, 0);
    }
  };

  // prologue: 2 tiles in flight (12 loads)
  STAGE(0, 0);
  STAGE(1, 1);

  for (int kt = 0; kt < NT - 1; ++kt) {
    asm volatile("s_waitcnt vmcnt(6)" ::: "memory");   // tile kt retired; kt+1 in flight
    __builtin_amdgcn_s_barrier();                      // all waves' writes visible
    __builtin_amdgcn_sched_barrier(0);
    COMPUTE(kt & 1);
    __builtin_amdgcn_sched_barrier(0);
    __builtin_amdgcn_s_barrier();                      // all waves done reading buf
    __builtin_amdgcn_sched_barrier(0);
    if (kt + 2 < NT) STAGE(kt + 2, kt & 1);            // refill freed buffer
  }
  asm volatile("s_waitcnt vmcnt(0)" ::: "memory");     // peeled last iteration
  __builtin_amdgcn_s_barrier();
  __builtin_amdgcn_sched_barrier(0);
  COMPUTE((NT - 1) & 1);

  // epilogue: C row = m0+wm+mi*16+(l>>4)*4+r ; col = n0+wn+ni*16+(l&15)
#pragma unroll
  for (int mi = 0; mi < 2; ++mi) {
    const int row = m0 + wm + mi * 16 + (l >> 4) * 4;
#pragma unroll
    for (int ni = 0; ni < 4; ++ni) {
      const int col = n0 + wn + ni * 16 + (l & 15);
      if (OUTMODE == 1 && col >= ncols) continue;
      const float bv = bias[col];
#pragma unroll
      for (int r = 0; r < 4; ++r) {
        float v = acc[mi][ni][r] + bv;
        if (OUTMODE == 0) {
          v = fmaxf(v, 0.f);
          Cb[(size_t)(row + r) * ldc + col] = f32_to_bf16(v);
        } else {
          Cf[(size_t)(row + r) * ldc + col] = v;
        }
      }
    }
  }
}

// ---------------- QP solve + log_softmax ----------------
// 4 waves/block, ONE problem per wave (2048 waves -> 2 waves/SIMD). Broadcasts
// via v_readlane (VALU pipe). Waves fully independent: no __syncthreads.
__global__ __launch_bounds__(256) void qp_kernel(const float* __restrict__ y,
                                                 float* __restrict__ out) {
  __shared__ float Gs[4][MMq][132];    // row pad 132: staging/epilogue conflict-free
  __shared__ float GGs[4][MMq][21];    // row pad 21: gcd(21,32)=1, conflict-free
  __shared__ float cs[4][MMq];
  const int tid = threadIdx.x;
  const int wid = tid >> 6, l = tid & 63;
  const int b = blockIdx.x * 4 + wid;
  const float* yb = y + (size_t)b * NY;

  // stage G (20x128) -- own wave only
  for (int idx = l; idx < MMq * NCq / 4; idx += 64) {
    const int r = idx >> 5;
    const int kk = (idx & 31) * 4;
    float4 v = ((const float4*)yb)[idx];
    *(float4*)&Gs[wid][r][kk] = v;
  }

  // GG = G G^T (upper triangle, mirrored) -- own wave
  for (int idx = l; idx < 210; idx += 64) {
    int i = 0, rem = idx;
    while (rem >= MMq - i) { rem -= MMq - i; ++i; }
    const int j = i + rem;
    float s = 0.f;
    for (int kk = 0; kk < NCq; kk += 4) {
      float4 a = *(const float4*)&Gs[wid][i][kk];
      float4 c4 = *(const float4*)&Gs[wid][j][kk];
      s += a.x * c4.x + a.y * c4.y + a.z * c4.z + a.w * c4.w;
    }
    GGs[wid][i][j] = s;
    GGs[wid][j][i] = s;
  }
  // c_i = sum_j G_ij + h_i
  if (l < MMq) {
    float s = 0.f;
    for (int kk = 0; kk < NCq; kk += 4) {
      float4 a = *(const float4*)&Gs[wid][l][kk];
      s += (a.x + a.y) + (a.z + a.w);
    }
    cs[wid][l] = s + yb[MMq * NCq + l];
  }

  const bool act = (l < MMq);
  float gg[MMq];
#pragma unroll
  for (int j = 0; j < MMq; ++j) gg[j] = act ? GGs[wid][l][j] : 0.f;
  const float ci = act ? cs[wid][l] : 0.f;

  // L = max_i sum_j |GG_ij| (inf-norm >= lambda_max; fixed point step-independent)
  float rs = 0.f;
#pragma unroll
  for (int j = 0; j < MMq; ++j) rs += fabsf(gg[j]);
#pragma unroll
  for (int m = 1; m < 64; m <<= 1) rs = fmaxf(rs, __shfl_xor(rs, m, 64));
  const float invL = 1.0f / (rs + 1e-6f);

  // FISTA, momentum beta_k = k/(k+3)
  float lam = 0.f, yv = 0.f, fi = 0.f;
  for (int it = 0; it < QP_ITERS; ++it) {
    float ys[MMq];
#pragma unroll
    for (int j = 0; j < MMq; ++j) ys[j] = bcast(yv, j);   // 20x v_readlane -> SGPR
    float g0 = ci, g1 = 0.f, g2 = 0.f, g3 = 0.f;
#pragma unroll
    for (int j = 0; j < MMq; j += 4) {
      g0 = fmaf(gg[j + 0], ys[j + 0], g0);
      g1 = fmaf(gg[j + 1], ys[j + 1], g1);
      g2 = fmaf(gg[j + 2], ys[j + 2], g2);
      g3 = fmaf(gg[j + 3], ys[j + 3], g3);
    }
    const float grad = (g0 + g1) + (g2 + g3);
    const float ln = fmaxf(fmaf(-grad, invL, yv), 0.f);
    const float beta = fi * __builtin_amdgcn_rcpf(fi + 3.0f);  // off critical path
    yv = fmaf(beta, ln - lam, ln);
    lam = ln;
    fi += 1.0f;
  }

  // broadcast lam to SGPRs; z_j = -(1 + sum_i G_ij lam_i); log_softmax over 128
  float ls[MMq];
#pragma unroll
  for (int j = 0; j < MMq; ++j) ls[j] = bcast(lam, j);

  float z0 = 1.f, z1 = 1.f;
#pragma unroll
  for (int ii = 0; ii < MMq; ++ii) {
    z0 = fmaf(Gs[wid][ii][l], ls[ii], z0);
    z1 = fmaf(Gs[wid][ii][l + 64], ls[ii], z1);
  }
  z0 = -z0; z1 = -z1;

  float mx = fmaxf(z0, z1);
#pragma unroll
  for (int m = 1; m < 64; m <<= 1) mx = fmaxf(mx, __shfl_xor(mx, m, 64));
  float sm = __expf(z0 - mx) + __expf(z1 - mx);
#pragma unroll
  for (int m = 1; m < 64; m <<= 1) sm += __shfl_xor(sm, m, 64);
  const float lse = mx + __logf(sm);
  float* ob = out + (size_t)b * NCq;
  ob[l] = z0 - lse;
  ob[l + 64] = z1 - lse;
}

// ---------------- launch ----------------
extern "C" void kernel_launch(void* const* d_in, const int* in_sizes, int n_in,
                              void* d_out, int out_size, void* d_ws, size_t ws_size,
                              hipStream_t stream) {
  const float* x  = (const float*)d_in[0];
  const float* W1 = (const float*)d_in[1];
  const float* b1 = (const float*)d_in[2];
  const float* W2 = (const float*)d_in[3];
  const float* b2 = (const float*)d_in[4];
  float* out = (float*)d_out;
  char* ws = (char*)d_ws;

  u16*   xb  = (u16*)(ws);                       //  4 MiB: 2048x1024 bf16
  u16*   w1b = (u16*)(ws + 4194304);             //  4 MiB: 2048x1024 bf16
  u16*   w2b = (u16*)(ws + 8388608);             // 10.5 MiB: 2688x2048 bf16 (pad rows
                                                 //   never stored -> left stale, safe)
  u16*   h1b = (u16*)(ws + 19398656);            //  8 MiB: 2048x2048 bf16
  float* yb  = (float*)(ws + 27787264);          // 20.2 MiB: 2048x2580 f32

  cvt_all_kernel<<<CVT_TOT / 256, 256, 0, stream>>>(x, W1, W2, xb, w1b, w2b);

  dim3 g1(NH / 128, B_SZ / 64);
  gemm_bt_kernel<NF, 0><<<g1, 256, 0, stream>>>(xb, w1b, b1, h1b, nullptr, NH, NH);

  dim3 g2(NYPAD / 128, B_SZ / 64);
  gemm_bt_kernel<NH, 1><<<g2, 256, 0, stream>>>(h1b, w2b, b2, nullptr, yb, NY, NY);

  qp_kernel<<<B_SZ / 4, 256, 0, stream>>>(yb, out);
}

// Round 12
// 98.863 us; speedup vs baseline: 1.2038x; 1.0872x over previous
//
#include <hip/hip_runtime.h>
#include <hip/hip_bf16.h>
#include <math.h>

#define B_SZ 2048
#define NF 1024
#define NH 2048
#define NCq 128
#define MMq 20
#define NY 2580            // M*NC+M
#define NYPAD 2688         // 21*128
#define QP_ITERS 120

#define XN4  (B_SZ * NF / 4)
#define W1N4 (NH * NF / 4)
#define W2N4 (NY * NH / 4)
#define CVT_TOT (XN4 + W1N4 + W2N4)

typedef unsigned short u16;
typedef __bf16 bf16x8 __attribute__((ext_vector_type(8)));
typedef float f32x4 __attribute__((ext_vector_type(4)));

static __device__ __forceinline__ u16 f32_to_bf16(float f) {
  unsigned u = __float_as_uint(f);
  u += 0x7FFFu + ((u >> 16) & 1u);
  return (u16)(u >> 16);
}

static __device__ __forceinline__ float bcast(float v, int lane) {
  return __uint_as_float(__builtin_amdgcn_readlane(__float_as_uint(v), lane));
}

static __device__ __forceinline__ void gload16(const void* g, void* lds) {
  __builtin_amdgcn_global_load_lds(
      (const __attribute__((address_space(1))) void*)g,
      (__attribute__((address_space(3))) void*)lds, 16, 0, 0);
}

// ---------------- single fused convert: x | W1 | W2(real rows) ----------------
__global__ __launch_bounds__(256) void cvt_all_kernel(const float* __restrict__ x,
                                                      const float* __restrict__ W1,
                                                      const float* __restrict__ W2,
                                                      u16* __restrict__ xb,
                                                      u16* __restrict__ w1b,
                                                      u16* __restrict__ w2b) {
  const int i = blockIdx.x * 256 + threadIdx.x;
  const float* src;
  u16* dst;
  int j;
  if (i < XN4)              { src = x;  dst = xb;  j = i; }
  else if (i < XN4 + W1N4)  { src = W1; dst = w1b; j = i - XN4; }
  else                      { src = W2; dst = w2b; j = i - XN4 - W1N4; }
  float4 v = ((const float4*)src)[j];
  ushort4 o;
  o.x = f32_to_bf16(v.x); o.y = f32_to_bf16(v.y);
  o.z = f32_to_bf16(v.z); o.w = f32_to_bf16(v.w);
  ((ushort4*)dst)[j] = o;
}

// ---------------- GEMM: C = A(MxK) * B(NxK)^T + bias, tile 64x128 ----------------
// Depth-2 counted-vmcnt pipeline (R11) + T2 both-sides LDS swizzle: logical
// k-chunk kp of row r stored at physical chunk kp ^ ((r>>1)&3) (16B granularity).
// gload_lds dest stays LINEAR (rule #21); the permutation is applied to the
// per-lane GLOBAL source address and to the ds_read offset. Bank spread per
// 16-lane read group: 2 lanes/bank = free (was 8-way, 4.1M conflicts/dispatch).
// 1D grid + bijective XCD swizzle (grid%8==0): consecutive swz share A-panel.
// OUTMODE 0: bf16 out with relu (gemm1). OUTMODE 1: f32 out, col<ncols guard (gemm2).
template<int K, int OUTMODE>
__global__ __launch_bounds__(256) void gemm_bt_kernel(
    const u16* __restrict__ A, const u16* __restrict__ Bm,
    const float* __restrict__ bias,
    u16* __restrict__ Cb, float* __restrict__ Cf,
    int ldc, int ncols, int nxt) {
  __shared__ u16 As[2][2][64 * 32];    // [buf][ksub] 4 KB planes, 16 KB
  __shared__ u16 Bs[2][2][128 * 32];   // [buf][ksub] 8 KB planes, 32 KB
  const int tid = threadIdx.x;
  const int w = tid >> 6;
  const int l = tid & 63;

  // bijective XCD swizzle: gridDim.x % 8 == 0 (512 / 672)
  const int chunk = gridDim.x >> 3;
  const int swz = (blockIdx.x & 7) * chunk + (blockIdx.x >> 3);
  const int m0 = (swz / nxt) * 64;
  const int n0 = (swz % nxt) * 128;

  // staging: physical chunk p=tid per plane -> row p>>2, phys-kp p&3;
  // logical k-chunk = (p&3) ^ f(row), f(row) = (row>>1)&3
  const int srow = tid >> 2;
  const int kps = (tid & 3) ^ ((tid >> 3) & 3);
  const u16* gA0 = A  + (size_t)(m0 + srow) * K + kps * 8;
  const u16* gB0 = Bm + (size_t)(n0 + srow) * K + kps * 8;
  const u16* gB1 = Bm + (size_t)(n0 + 64 + srow) * K + kps * 8;
  char* lA = (char*)As;
  char* lB = (char*)Bs;
  const int lbW = w * 1024;            // wave-uniform byte offset within a plane

  // wave -> 32x64 output sub-tile: wm in {0,32}, wn in {0,64}
  const int wm = (w >> 1) * 32, wn = (w & 1) * 64;
  const int lrow = l & 15;
  const int kc = ((l >> 4) ^ ((lrow >> 1) & 3)) * 16;   // swizzled 16B chunk
  int aoff[2], boff[4];
#pragma unroll
  for (int i = 0; i < 2; ++i) aoff[i] = (wm + i * 16 + lrow) * 64 + kc;
#pragma unroll
  for (int i = 0; i < 4; ++i) boff[i] = (wn + i * 16 + lrow) * 64 + kc;

  f32x4 acc[2][4];
#pragma unroll
  for (int i = 0; i < 2; ++i)
#pragma unroll
    for (int j = 0; j < 4; ++j) acc[i][j] = (f32x4){0.f, 0.f, 0.f, 0.f};

  constexpr int NT = K / 64;           // gemm1: 16, gemm2: 32

  auto STAGE = [&](int t, int buf) {   // 6 gload16
#pragma unroll
    for (int ks = 0; ks < 2; ++ks) {
      const int koff = t * 64 + ks * 32;
      gload16(gA0 + koff, lA + buf * 8192  + ks * 4096 + lbW);
      gload16(gB0 + koff, lB + buf * 16384 + ks * 8192 + lbW);
      gload16(gB1 + koff, lB + buf * 16384 + ks * 8192 + 4096 + lbW);
    }
  };
  auto COMPUTE = [&](int buf) {        // 12 ds_read_b128 + 16 MFMA
#pragma unroll
    for (int ks = 0; ks < 2; ++ks) {
      const char* pa = lA + buf * 8192  + ks * 4096;
      const char* pb = lB + buf * 16384 + ks * 8192;
      bf16x8 af[2], bfr[4];
#pragma unroll
      for (int i = 0; i < 2; ++i) af[i] = *(const bf16x8*)(pa + aoff[i]);
#pragma unroll
      for (int i = 0; i < 4; ++i) bfr[i] = *(const bf16x8*)(pb + boff[i]);
#pragma unroll
      for (int mi = 0; mi < 2; ++mi)
#pragma unroll
        for (int ni = 0; ni < 4; ++ni)
          acc[mi][ni] = __builtin_amdgcn_mfma_f32_16x16x32_bf16(af[mi], bfr[ni], acc[mi][ni], 0, 0, 0);
    }
  };

  // prologue: 2 tiles in flight (12 loads)
  STAGE(0, 0);
  STAGE(1, 1);

  for (int kt = 0; kt < NT - 1; ++kt) {
    asm volatile("s_waitcnt vmcnt(6)" ::: "memory");   // tile kt retired; kt+1 in flight
    __builtin_amdgcn_s_barrier();                      // all waves' writes visible
    __builtin_amdgcn_sched_barrier(0);
    COMPUTE(kt & 1);
    __builtin_amdgcn_sched_barrier(0);
    __builtin_amdgcn_s_barrier();                      // all waves done reading buf
    __builtin_amdgcn_sched_barrier(0);
    if (kt + 2 < NT) STAGE(kt + 2, kt & 1);            // refill freed buffer
  }
  asm volatile("s_waitcnt vmcnt(0)" ::: "memory");     // peeled last iteration
  __builtin_amdgcn_s_barrier();
  __builtin_amdgcn_sched_barrier(0);
  COMPUTE((NT - 1) & 1);

  // epilogue: C row = m0+wm+mi*16+(l>>4)*4+r ; col = n0+wn+ni*16+(l&15)
#pragma unroll
  for (int mi = 0; mi < 2; ++mi) {
    const int row = m0 + wm + mi * 16 + (l >> 4) * 4;
#pragma unroll
    for (int ni = 0; ni < 4; ++ni) {
      const int col = n0 + wn + ni * 16 + (l & 15);
      if (OUTMODE == 1 && col >= ncols) continue;
      const float bv = bias[col];
#pragma unroll
      for (int r = 0; r < 4; ++r) {
        float v = acc[mi][ni][r] + bv;
        if (OUTMODE == 0) {
          v = fmaxf(v, 0.f);
          Cb[(size_t)(row + r) * ldc + col] = f32_to_bf16(v);
        } else {
          Cf[(size_t)(row + r) * ldc + col] = v;
        }
      }
    }
  }
}

// ---------------- QP solve + log_softmax ----------------
// 4 waves/block, ONE problem per wave (2048 waves -> 2 waves/SIMD). Broadcasts
// via v_readlane (VALU pipe). Waves fully independent: no __syncthreads.
__global__ __launch_bounds__(256) void qp_kernel(const float* __restrict__ y,
                                                 float* __restrict__ out) {
  __shared__ float Gs[4][MMq][132];    // row pad 132: staging/epilogue conflict-free
  __shared__ float GGs[4][MMq][21];    // row pad 21: gcd(21,32)=1, conflict-free
  __shared__ float cs[4][MMq];
  const int tid = threadIdx.x;
  const int wid = tid >> 6, l = tid & 63;
  const int b = blockIdx.x * 4 + wid;
  const float* yb = y + (size_t)b * NY;

  // stage G (20x128) -- own wave only
  for (int idx = l; idx < MMq * NCq / 4; idx += 64) {
    const int r = idx >> 5;
    const int kk = (idx & 31) * 4;
    float4 v = ((const float4*)yb)[idx];
    *(float4*)&Gs[wid][r][kk] = v;
  }

  // GG = G G^T (upper triangle, mirrored) -- own wave
  for (int idx = l; idx < 210; idx += 64) {
    int i = 0, rem = idx;
    while (rem >= MMq - i) { rem -= MMq - i; ++i; }
    const int j = i + rem;
    float s = 0.f;
    for (int kk = 0; kk < NCq; kk += 4) {
      float4 a = *(const float4*)&Gs[wid][i][kk];
      float4 c4 = *(const float4*)&Gs[wid][j][kk];
      s += a.x * c4.x + a.y * c4.y + a.z * c4.z + a.w * c4.w;
    }
    GGs[wid][i][j] = s;
    GGs[wid][j][i] = s;
  }
  // c_i = sum_j G_ij + h_i
  if (l < MMq) {
    float s = 0.f;
    for (int kk = 0; kk < NCq; kk += 4) {
      float4 a = *(const float4*)&Gs[wid][l][kk];
      s += (a.x + a.y) + (a.z + a.w);
    }
    cs[wid][l] = s + yb[MMq * NCq + l];
  }

  const bool act = (l < MMq);
  float gg[MMq];
#pragma unroll
  for (int j = 0; j < MMq; ++j) gg[j] = act ? GGs[wid][l][j] : 0.f;
  const float ci = act ? cs[wid][l] : 0.f;

  // L = max_i sum_j |GG_ij| (inf-norm >= lambda_max; fixed point step-independent)
  float rs = 0.f;
#pragma unroll
  for (int j = 0; j < MMq; ++j) rs += fabsf(gg[j]);
#pragma unroll
  for (int m = 1; m < 64; m <<= 1) rs = fmaxf(rs, __shfl_xor(rs, m, 64));
  const float invL = 1.0f / (rs + 1e-6f);

  // FISTA, momentum beta_k = k/(k+3)
  float lam = 0.f, yv = 0.f, fi = 0.f;
  for (int it = 0; it < QP_ITERS; ++it) {
    float ys[MMq];
#pragma unroll
    for (int j = 0; j < MMq; ++j) ys[j] = bcast(yv, j);   // 20x v_readlane -> SGPR
    float g0 = ci, g1 = 0.f, g2 = 0.f, g3 = 0.f;
#pragma unroll
    for (int j = 0; j < MMq; j += 4) {
      g0 = fmaf(gg[j + 0], ys[j + 0], g0);
      g1 = fmaf(gg[j + 1], ys[j + 1], g1);
      g2 = fmaf(gg[j + 2], ys[j + 2], g2);
      g3 = fmaf(gg[j + 3], ys[j + 3], g3);
    }
    const float grad = (g0 + g1) + (g2 + g3);
    const float ln = fmaxf(fmaf(-grad, invL, yv), 0.f);
    const float beta = fi * __builtin_amdgcn_rcpf(fi + 3.0f);  // off critical path
    yv = fmaf(beta, ln - lam, ln);
    lam = ln;
    fi += 1.0f;
  }

  // broadcast lam to SGPRs; z_j = -(1 + sum_i G_ij lam_i); log_softmax over 128
  float ls[MMq];
#pragma unroll
  for (int j = 0; j < MMq; ++j) ls[j] = bcast(lam, j);

  float z0 = 1.f, z1 = 1.f;
#pragma unroll
  for (int ii = 0; ii < MMq; ++ii) {
    z0 = fmaf(Gs[wid][ii][l], ls[ii], z0);
    z1 = fmaf(Gs[wid][ii][l + 64], ls[ii], z1);
  }
  z0 = -z0; z1 = -z1;

  float mx = fmaxf(z0, z1);
#pragma unroll
  for (int m = 1; m < 64; m <<= 1) mx = fmaxf(mx, __shfl_xor(mx, m, 64));
  float sm = __expf(z0 - mx) + __expf(z1 - mx);
#pragma unroll
  for (int m = 1; m < 64; m <<= 1) sm += __shfl_xor(sm, m, 64);
  const float lse = mx + __logf(sm);
  float* ob = out + (size_t)b * NCq;
  ob[l] = z0 - lse;
  ob[l + 64] = z1 - lse;
}

// ---------------- launch ----------------
extern "C" void kernel_launch(void* const* d_in, const int* in_sizes, int n_in,
                              void* d_out, int out_size, void* d_ws, size_t ws_size,
                              hipStream_t stream) {
  const float* x  = (const float*)d_in[0];
  const float* W1 = (const float*)d_in[1];
  const float* b1 = (const float*)d_in[2];
  const float* W2 = (const float*)d_in[3];
  const float* b2 = (const float*)d_in[4];
  float* out = (float*)d_out;
  char* ws = (char*)d_ws;

  u16*   xb  = (u16*)(ws);                       //  4 MiB: 2048x1024 bf16
  u16*   w1b = (u16*)(ws + 4194304);             //  4 MiB: 2048x1024 bf16
  u16*   w2b = (u16*)(ws + 8388608);             // 10.5 MiB: 2688x2048 bf16 (pad rows
                                                 //   never stored -> left stale, safe)
  u16*   h1b = (u16*)(ws + 19398656);            //  8 MiB: 2048x2048 bf16
  float* yb  = (float*)(ws + 27787264);          // 20.2 MiB: 2048x2580 f32

  cvt_all_kernel<<<CVT_TOT / 256, 256, 0, stream>>>(x, W1, W2, xb, w1b, w2b);

  // 1D grids, both %8==0 for the bijective XCD swizzle
  gemm_bt_kernel<NF, 0><<<(NH / 128) * (B_SZ / 64), 256, 0, stream>>>(
      xb, w1b, b1, h1b, nullptr, NH, NH, NH / 128);

  gemm_bt_kernel<NH, 1><<<(NYPAD / 128) * (B_SZ / 64), 256, 0, stream>>>(
      h1b, w2b, b2, nullptr, yb, NY, NY, NYPAD / 128);

  qp_kernel<<<B_SZ / 4, 256, 0, stream>>>(yb, out);
}